// Round 1
// baseline (679.218 us; speedup 1.0000x reference)
//
#include <hip/hip_runtime.h>
#include <math.h>

#define N_NODES 50000
#define D 256
#define NSAMP 5
#define LN_EPS 1e-5f
#define GEMM_ROWS 16

// ---------------------------------------------------------------------------
// K0: h[N][256] = x[N][256] @ w[256][256]  (fp32, LDS-staged x tile)
// ---------------------------------------------------------------------------
__global__ __launch_bounds__(256) void gemm_kernel(const float* __restrict__ x,
                                                   const float* __restrict__ w,
                                                   float* __restrict__ h) {
    __shared__ float xs[GEMM_ROWS][D];
    const int j  = threadIdx.x;                 // output column 0..255
    const int i0 = blockIdx.x * GEMM_ROWS;      // first row of this block's tile

    // stage x tile (16 rows x 256 cols = 4096 floats) via float4
    const float4* xv  = (const float4*)(x + (size_t)i0 * D);
    float4*       xsv = (float4*)&xs[0][0];
#pragma unroll
    for (int t = 0; t < 4; ++t) xsv[j + 256 * t] = xv[j + 256 * t];
    __syncthreads();

    float acc[GEMM_ROWS];
#pragma unroll
    for (int r = 0; r < GEMM_ROWS; ++r) acc[r] = 0.f;

    for (int k = 0; k < D; k += 4) {
        const float w0 = w[(size_t)(k + 0) * D + j];
        const float w1 = w[(size_t)(k + 1) * D + j];
        const float w2 = w[(size_t)(k + 2) * D + j];
        const float w3 = w[(size_t)(k + 3) * D + j];
#pragma unroll
        for (int r = 0; r < GEMM_ROWS; ++r) {
            const float4 xr = *(const float4*)&xs[r][k];   // LDS broadcast read
            acc[r] += xr.x * w0 + xr.y * w1 + xr.z * w2 + xr.w * w3;
        }
    }
#pragma unroll
    for (int r = 0; r < GEMM_ROWS; ++r)
        h[(size_t)(i0 + r) * D + j] = acc[r];
}

// ---------------------------------------------------------------------------
// K1: histogram of edge rows
// ---------------------------------------------------------------------------
__global__ void hist_kernel(const int* __restrict__ rows, int* __restrict__ cnt, int E) {
    int e = blockIdx.x * blockDim.x + threadIdx.x;
    if (e < E) atomicAdd(&cnt[rows[e]], 1);
}

// ---------------------------------------------------------------------------
// K2: single-block exclusive scan of cnt[N] -> off[N+1], cursor[N]
// ---------------------------------------------------------------------------
__global__ __launch_bounds__(1024) void scan_kernel(const int* __restrict__ cnt,
                                                    int* __restrict__ off,
                                                    int* __restrict__ cursor, int n) {
    __shared__ int sums[1024];
    const int tid = threadIdx.x;
    const int per = (n + 1023) / 1024;
    const int start = tid * per;
    const int end = min(start + per, n);

    int s = 0;
    for (int i = start; i < end; ++i) s += cnt[i];
    sums[tid] = s;
    __syncthreads();

    // Hillis-Steele inclusive scan over 1024 partials
    for (int d = 1; d < 1024; d <<= 1) {
        int v = (tid >= d) ? sums[tid - d] : 0;
        __syncthreads();
        sums[tid] += v;
        __syncthreads();
    }

    int run = (tid > 0) ? sums[tid - 1] : 0;   // exclusive prefix of this chunk
    for (int i = start; i < end; ++i) {
        off[i] = run;
        cursor[i] = run;
        run += cnt[i];
    }
    if (tid == 1023) off[n] = sums[1023];
}

// ---------------------------------------------------------------------------
// K3: scatter edges into CSR order
// ---------------------------------------------------------------------------
__global__ void scatter_kernel(const int* __restrict__ rows, const int* __restrict__ cols,
                               const float* __restrict__ vals, int* __restrict__ cursor,
                               int* __restrict__ ecol, float* __restrict__ eval, int E) {
    int e = blockIdx.x * blockDim.x + threadIdx.x;
    if (e < E) {
        int r = rows[e];
        int p = atomicAdd(&cursor[r], 1);
        ecol[p] = cols[e];
        eval[p] = vals[e];
    }
}

// ---------------------------------------------------------------------------
// K4: per-row fused SpMM + bias + ELU + LayerNorm + mask-expand
// One wave (64 lanes) per row; lane l owns dims [4l, 4l+3].
// ---------------------------------------------------------------------------
__global__ __launch_bounds__(256) void row_kernel(const float* __restrict__ h,
                                                  const int* __restrict__ off,
                                                  const int* __restrict__ ecol,
                                                  const float* __restrict__ eval,
                                                  const float* __restrict__ bias,
                                                  const float* __restrict__ gamma,
                                                  const float* __restrict__ beta,
                                                  const float* __restrict__ mask,
                                                  float* __restrict__ out, int n) {
    const int wave = threadIdx.x >> 6;
    const int lane = threadIdx.x & 63;
    const int r = blockIdx.x * 4 + wave;
    if (r >= n) return;

    const int s = off[r];
    const int e = off[r + 1];

    float4 acc = {0.f, 0.f, 0.f, 0.f};
    int i = s;
    // unroll-by-2 for a little ILP on the dependent gather chain
    for (; i + 1 < e; i += 2) {
        const int   c0 = ecol[i],     c1 = ecol[i + 1];
        const float v0 = eval[i],     v1 = eval[i + 1];
        const float4 h0 = *(const float4*)(h + (size_t)c0 * D + lane * 4);
        const float4 h1 = *(const float4*)(h + (size_t)c1 * D + lane * 4);
        acc.x += v0 * h0.x + v1 * h1.x;
        acc.y += v0 * h0.y + v1 * h1.y;
        acc.z += v0 * h0.z + v1 * h1.z;
        acc.w += v0 * h0.w + v1 * h1.w;
    }
    if (i < e) {
        const int   c0 = ecol[i];
        const float v0 = eval[i];
        const float4 h0 = *(const float4*)(h + (size_t)c0 * D + lane * 4);
        acc.x += v0 * h0.x;
        acc.y += v0 * h0.y;
        acc.z += v0 * h0.z;
        acc.w += v0 * h0.w;
    }

    // bias + ELU
    const float4 b4 = *(const float4*)(bias + lane * 4);
    float x0 = acc.x + b4.x;
    float x1 = acc.y + b4.y;
    float x2 = acc.z + b4.z;
    float x3 = acc.w + b4.w;
    x0 = x0 > 0.f ? x0 : expm1f(x0);
    x1 = x1 > 0.f ? x1 : expm1f(x1);
    x2 = x2 > 0.f ? x2 : expm1f(x2);
    x3 = x3 > 0.f ? x3 : expm1f(x3);

    // LayerNorm over 256 dims: wave-wide reduce of sum and sumsq
    float s1 = x0 + x1 + x2 + x3;
    float s2 = x0 * x0 + x1 * x1 + x2 * x2 + x3 * x3;
#pragma unroll
    for (int d = 1; d < 64; d <<= 1) {
        s1 += __shfl_xor(s1, d);
        s2 += __shfl_xor(s2, d);
    }
    const float mu   = s1 * (1.f / 256.f);
    const float var  = s2 * (1.f / 256.f) - mu * mu;
    const float rsig = rsqrtf(var + LN_EPS);

    const float4 g4  = *(const float4*)(gamma + lane * 4);
    const float4 be4 = *(const float4*)(beta + lane * 4);
    const float y0 = (x0 - mu) * rsig * g4.x + be4.x;
    const float y1 = (x1 - mu) * rsig * g4.y + be4.y;
    const float y2 = (x2 - mu) * rsig * g4.z + be4.z;
    const float y3 = (x3 - mu) * rsig * g4.w + be4.w;

    // expand to 5 samples with per-sample mask
#pragma unroll
    for (int smp = 0; smp < NSAMP; ++smp) {
        const float4 m4 = *(const float4*)(mask + smp * D + lane * 4);
        float4 o;
        o.x = y0 * m4.x;
        o.y = y1 * m4.y;
        o.z = y2 * m4.z;
        o.w = y3 * m4.w;
        *(float4*)(out + ((size_t)r * NSAMP + smp) * D + lane * 4) = o;
    }
}

// ---------------------------------------------------------------------------
extern "C" void kernel_launch(void* const* d_in, const int* in_sizes, int n_in,
                              void* d_out, int out_size, void* d_ws, size_t ws_size,
                              hipStream_t stream) {
    const float* x     = (const float*)d_in[0];
    const int*   adj   = (const int*)d_in[1];   // [2][E]: rows then cols
    const float* vals  = (const float*)d_in[2];
    const float* mask  = (const float*)d_in[3];
    const float* w     = (const float*)d_in[4];
    const float* bias  = (const float*)d_in[5];
    const float* gamma = (const float*)d_in[6];
    const float* beta  = (const float*)d_in[7];
    float*       out   = (float*)d_out;

    const int N = N_NODES;
    const int E = in_sizes[2];                  // adj_values element count

    // workspace layout (bytes):
    //   h:     N*256*4   = 51,200,000
    //   cnt:   N*4
    //   off:   (N+1)*4
    //   cur:   N*4
    //   ecol:  E*4
    //   eval:  E*4       -> total ~64.6 MB
    char*  ws   = (char*)d_ws;
    float* h    = (float*)ws;
    int*   cnt  = (int*)(ws + (size_t)N * D * sizeof(float));
    int*   roff = cnt + N;
    int*   cur  = roff + (N + 1);
    int*   ecol = cur + N;
    float* eval = (float*)(ecol + E);

    hipMemsetAsync(cnt, 0, (size_t)N * sizeof(int), stream);

    gemm_kernel<<<N / GEMM_ROWS, 256, 0, stream>>>(x, w, h);
    hist_kernel<<<(E + 255) / 256, 256, 0, stream>>>(adj, cnt, E);
    scan_kernel<<<1, 1024, 0, stream>>>(cnt, roff, cur, N);
    scatter_kernel<<<(E + 255) / 256, 256, 0, stream>>>(adj, adj + E, vals, cur, ecol, eval, E);
    row_kernel<<<(N + 3) / 4, 256, 0, stream>>>(h, roff, ecol, eval, bias, gamma, beta, mask, out, N);
}

// Round 2
// 411.803 us; speedup vs baseline: 1.6494x; 1.6494x over previous
//
#include <hip/hip_runtime.h>
#include <math.h>

#define NNODES 50000
#define D 256
#define NSAMP 5
#define LN_EPS 1e-5f

typedef __bf16 bf16;
typedef __attribute__((ext_vector_type(8))) __bf16 bf16x8;
typedef __attribute__((ext_vector_type(4))) float f32x4;

__device__ inline float bflo(unsigned int u) { return __uint_as_float(u << 16); }
__device__ inline float bfhi(unsigned int u) { return __uint_as_float(u & 0xffff0000u); }

// ---------------------------------------------------------------------------
// K_prep: w[256][256] fp32 -> wt[n][k] bf16 (transposed)
// ---------------------------------------------------------------------------
__global__ void wprep_kernel(const float* __restrict__ w, bf16* __restrict__ wt) {
    const int n = blockIdx.x;     // 0..255
    const int k = threadIdx.x;    // 0..255
    wt[(size_t)n * D + k] = (bf16)w[(size_t)k * D + n];
}

// ---------------------------------------------------------------------------
// K0: h[N][256] (bf16) = x[N][256] @ w  via mfma_f32_16x16x32_bf16
// block = 256 threads = 4 waves; wave handles 16 rows x 256 cols
// ---------------------------------------------------------------------------
__global__ __launch_bounds__(256) void gemm_mfma(const float* __restrict__ x,
                                                 const bf16* __restrict__ wt,
                                                 bf16* __restrict__ h) {
    const int wave = threadIdx.x >> 6;
    const int lane = threadIdx.x & 63;
    const int row0 = blockIdx.x * 64 + wave * 16;  // this wave's 16 rows
    const int am = lane & 15;                      // A row / B col within tile
    const int ag = lane >> 4;                      // k-group

    int arow = row0 + am;
    if (arow >= NNODES) arow = NNODES - 1;         // clamp loads; stores guarded

    f32x4 acc[16];
#pragma unroll
    for (int n = 0; n < 16; ++n) acc[n] = (f32x4){0.f, 0.f, 0.f, 0.f};

#pragma unroll
    for (int kk = 0; kk < 8; ++kk) {
        const int kb = kk * 32 + ag * 8;
        const float* xp = x + (size_t)arow * D + kb;
        const f32x4 a0 = __builtin_nontemporal_load((const f32x4*)xp);
        const f32x4 a1 = __builtin_nontemporal_load((const f32x4*)(xp + 4));
        bf16x8 a;
        a[0] = (bf16)a0[0]; a[1] = (bf16)a0[1]; a[2] = (bf16)a0[2]; a[3] = (bf16)a0[3];
        a[4] = (bf16)a1[0]; a[5] = (bf16)a1[1]; a[6] = (bf16)a1[2]; a[7] = (bf16)a1[3];
#pragma unroll
        for (int n = 0; n < 16; ++n) {
            const bf16x8 b = *(const bf16x8*)(wt + (size_t)(n * 16 + am) * D + kb);
            acc[n] = __builtin_amdgcn_mfma_f32_16x16x32_bf16(a, b, acc[n], 0, 0, 0);
        }
    }

    // D mapping (verified): col = n*16 + (lane&15), row = (lane>>4)*4 + r
    const int drow = row0 + ag * 4;
#pragma unroll
    for (int r = 0; r < 4; ++r) {
        if (drow + r < NNODES) {
            bf16* hp = h + (size_t)(drow + r) * D + am;
#pragma unroll
            for (int n = 0; n < 16; ++n) hp[n * 16] = (bf16)acc[n][r];
        }
    }
}

// ---------------------------------------------------------------------------
// K1: histogram of edge rows
// ---------------------------------------------------------------------------
__global__ void hist_kernel(const int* __restrict__ rows, int* __restrict__ cnt, int E) {
    int e = blockIdx.x * blockDim.x + threadIdx.x;
    if (e < E) atomicAdd(&cnt[rows[e]], 1);
}

// ---------------------------------------------------------------------------
// K2: 3-phase exclusive scan of cnt[N] -> off[N+1], cursor[N]
// ---------------------------------------------------------------------------
__global__ __launch_bounds__(256) void scan_partial(const int* __restrict__ cnt,
                                                    int* __restrict__ part, int n) {
    const int i = blockIdx.x * 256 + threadIdx.x;
    int v = (i < n) ? cnt[i] : 0;
#pragma unroll
    for (int d = 1; d < 64; d <<= 1) v += __shfl_xor(v, d);
    __shared__ int ws[4];
    if ((threadIdx.x & 63) == 0) ws[threadIdx.x >> 6] = v;
    __syncthreads();
    if (threadIdx.x == 0) part[blockIdx.x] = ws[0] + ws[1] + ws[2] + ws[3];
}

__global__ __launch_bounds__(256) void scan_root(int* __restrict__ part, int nb) {
    __shared__ int s[256];
    const int tid = threadIdx.x;
    s[tid] = (tid < nb) ? part[tid] : 0;
    __syncthreads();
    for (int d = 1; d < 256; d <<= 1) {
        int t = (tid >= d) ? s[tid - d] : 0;
        __syncthreads();
        s[tid] += t;
        __syncthreads();
    }
    if (tid < nb) part[tid] = (tid ? s[tid - 1] : 0);  // exclusive
}

__global__ __launch_bounds__(256) void scan_final(const int* __restrict__ cnt,
                                                  const int* __restrict__ part,
                                                  int* __restrict__ off,
                                                  int* __restrict__ cur, int n) {
    const int i = blockIdx.x * 256 + threadIdx.x;
    const int lane = threadIdx.x & 63;
    const int w = threadIdx.x >> 6;
    const int v = (i < n) ? cnt[i] : 0;
    int inc = v;
#pragma unroll
    for (int d = 1; d < 64; d <<= 1) {
        int t = __shfl_up(inc, d);
        if (lane >= d) inc += t;
    }
    __shared__ int wsum[4];
    if (lane == 63) wsum[w] = inc;
    __syncthreads();
    int wo = 0;
    for (int j = 0; j < w; ++j) wo += wsum[j];
    const int excl = part[blockIdx.x] + wo + inc - v;
    if (i < n) { off[i] = excl; cur[i] = excl; }
    if (i == n - 1) off[n] = excl + v;
}

// ---------------------------------------------------------------------------
// K3: scatter edges into CSR order, packed (col, val) int2
// ---------------------------------------------------------------------------
__global__ void scatter_kernel(const int* __restrict__ rows, const int* __restrict__ cols,
                               const float* __restrict__ vals, int* __restrict__ cursor,
                               int2* __restrict__ ep, int E) {
    int e = blockIdx.x * blockDim.x + threadIdx.x;
    if (e < E) {
        const int r = rows[e];
        const int p = atomicAdd(&cursor[r], 1);
        ep[p] = make_int2(cols[e], __float_as_int(vals[e]));
    }
}

// ---------------------------------------------------------------------------
// K4: per-row fused SpMM(bf16 h) + bias + ELU + LayerNorm + mask-expand
// one wave per row; lane l owns dims [4l, 4l+3]
// ---------------------------------------------------------------------------
__global__ __launch_bounds__(256) void row_kernel(const unsigned short* __restrict__ hb,
                                                  const int* __restrict__ off,
                                                  const int2* __restrict__ ep,
                                                  const float* __restrict__ bias,
                                                  const float* __restrict__ gamma,
                                                  const float* __restrict__ beta,
                                                  const float* __restrict__ mask,
                                                  float* __restrict__ out, int n) {
    const int wave = threadIdx.x >> 6;
    const int lane = threadIdx.x & 63;
    const int r = blockIdx.x * 4 + wave;
    if (r >= n) return;

    const int s = off[r];
    const int e = off[r + 1];

    float a0 = 0.f, a1 = 0.f, a2 = 0.f, a3 = 0.f;
    int i = s;
    for (; i + 3 < e; i += 4) {
        const int2 e0 = ep[i], e1 = ep[i + 1], e2 = ep[i + 2], e3 = ep[i + 3];
        const uint2 q0 = *(const uint2*)(hb + (size_t)e0.x * D + lane * 4);
        const uint2 q1 = *(const uint2*)(hb + (size_t)e1.x * D + lane * 4);
        const uint2 q2 = *(const uint2*)(hb + (size_t)e2.x * D + lane * 4);
        const uint2 q3 = *(const uint2*)(hb + (size_t)e3.x * D + lane * 4);
        const float v0 = __int_as_float(e0.y), v1 = __int_as_float(e1.y);
        const float v2 = __int_as_float(e2.y), v3 = __int_as_float(e3.y);
        a0 += v0 * bflo(q0.x) + v1 * bflo(q1.x) + v2 * bflo(q2.x) + v3 * bflo(q3.x);
        a1 += v0 * bfhi(q0.x) + v1 * bfhi(q1.x) + v2 * bfhi(q2.x) + v3 * bfhi(q3.x);
        a2 += v0 * bflo(q0.y) + v1 * bflo(q1.y) + v2 * bflo(q2.y) + v3 * bflo(q3.y);
        a3 += v0 * bfhi(q0.y) + v1 * bfhi(q1.y) + v2 * bfhi(q2.y) + v3 * bfhi(q3.y);
    }
    for (; i < e; ++i) {
        const int2 e0 = ep[i];
        const uint2 q0 = *(const uint2*)(hb + (size_t)e0.x * D + lane * 4);
        const float v0 = __int_as_float(e0.y);
        a0 += v0 * bflo(q0.x);
        a1 += v0 * bfhi(q0.x);
        a2 += v0 * bflo(q0.y);
        a3 += v0 * bfhi(q0.y);
    }

    // bias + ELU
    const f32x4 b4 = *(const f32x4*)(bias + lane * 4);
    float x0 = a0 + b4[0], x1 = a1 + b4[1], x2 = a2 + b4[2], x3 = a3 + b4[3];
    x0 = x0 > 0.f ? x0 : expm1f(x0);
    x1 = x1 > 0.f ? x1 : expm1f(x1);
    x2 = x2 > 0.f ? x2 : expm1f(x2);
    x3 = x3 > 0.f ? x3 : expm1f(x3);

    // LayerNorm over 256 dims
    float s1 = x0 + x1 + x2 + x3;
    float s2 = x0 * x0 + x1 * x1 + x2 * x2 + x3 * x3;
#pragma unroll
    for (int d = 1; d < 64; d <<= 1) {
        s1 += __shfl_xor(s1, d);
        s2 += __shfl_xor(s2, d);
    }
    const float mu   = s1 * (1.f / 256.f);
    const float var  = s2 * (1.f / 256.f) - mu * mu;
    const float rsig = rsqrtf(var + LN_EPS);

    const f32x4 g4  = *(const f32x4*)(gamma + lane * 4);
    const f32x4 be4 = *(const f32x4*)(beta + lane * 4);
    const float y0 = (x0 - mu) * rsig * g4[0] + be4[0];
    const float y1 = (x1 - mu) * rsig * g4[1] + be4[1];
    const float y2 = (x2 - mu) * rsig * g4[2] + be4[2];
    const float y3 = (x3 - mu) * rsig * g4[3] + be4[3];

#pragma unroll
    for (int smp = 0; smp < NSAMP; ++smp) {
        const f32x4 m4 = *(const f32x4*)(mask + smp * D + lane * 4);
        f32x4 o;
        o[0] = y0 * m4[0];
        o[1] = y1 * m4[1];
        o[2] = y2 * m4[2];
        o[3] = y3 * m4[3];
        __builtin_nontemporal_store(o, (f32x4*)(out + ((size_t)r * NSAMP + smp) * D + lane * 4));
    }
}

// ---------------------------------------------------------------------------
extern "C" void kernel_launch(void* const* d_in, const int* in_sizes, int n_in,
                              void* d_out, int out_size, void* d_ws, size_t ws_size,
                              hipStream_t stream) {
    const float* x     = (const float*)d_in[0];
    const int*   adj   = (const int*)d_in[1];   // [2][E]: rows then cols
    const float* vals  = (const float*)d_in[2];
    const float* mask  = (const float*)d_in[3];
    const float* w     = (const float*)d_in[4];
    const float* bias  = (const float*)d_in[5];
    const float* gamma = (const float*)d_in[6];
    const float* beta  = (const float*)d_in[7];
    float*       out   = (float*)d_out;

    const int N = NNODES;
    const int E = in_sizes[2];
    const int NBLK = (N + 255) / 256;           // 196 scan blocks

    // workspace layout
    char* ws = (char*)d_ws;
    unsigned short* hb  = (unsigned short*)ws;                       // 25.6 MB bf16 h
    bf16*           wt  = (bf16*)(ws + (size_t)N * D * 2);           // 128 KB
    int*            cnt = (int*)((char*)wt + (size_t)D * D * 2);
    int*            cur = cnt + N;
    int*            off = cur + N;
    int*            part= off + (N + 8);
    int2*           ep  = (int2*)((char*)(part + 256) + 0);

    hipMemsetAsync(cnt, 0, (size_t)N * sizeof(int), stream);

    wprep_kernel<<<D, D, 0, stream>>>(w, wt);
    gemm_mfma<<<(N + 63) / 64, 256, 0, stream>>>(x, wt, (bf16*)hb);
    hist_kernel<<<(E + 255) / 256, 256, 0, stream>>>(adj, cnt, E);
    scan_partial<<<NBLK, 256, 0, stream>>>(cnt, part, N);
    scan_root<<<1, 256, 0, stream>>>(part, NBLK);
    scan_final<<<NBLK, 256, 0, stream>>>(cnt, part, off, cur, N);
    scatter_kernel<<<(E + 255) / 256, 256, 0, stream>>>(adj, adj + E, vals, cur, ep, E);
    row_kernel<<<(N + 3) / 4, 256, 0, stream>>>(hb, off, ep, bias, gamma, beta, mask, out, N);
}